// Round 1
// baseline (270.660 us; speedup 1.0000x reference)
//
#include <hip/hip_runtime.h>
#include <math.h>

#define UNITS 512
#define INPUT_DIM 512
#define BATCH 256
#define NUM_K (INPUT_DIM * 3 * UNITS)            // 786432
#define NUM_RK (UNITS * 3 * UNITS)               // 786432
#define NUM_B (2 * 3 * UNITS)                    // 3072
#define PARAM_DIM (NUM_K + NUM_RK + NUM_B)       // 1575936

// Block: 256 threads = 2 row-groups x 128 unit-lanes; each lane owns 2 units
// (float2 loads). Each block: one (batch, 256-unit chunk). Grid = BATCH*2.
__global__ __launch_bounds__(256) void gru_fused(
    const float* __restrict__ inputs,
    const float* __restrict__ params,
    const float* __restrict__ h_tm1,
    float* __restrict__ out)
{
    __shared__ float x_lds[INPUT_DIM];
    __shared__ float h_lds[UNITS];
    __shared__ float red[128][13];   // 12 partials + pad (stride 13: conflict-free)

    const int tid   = threadIdx.x;
    const int ulane = tid & 127;
    const int rg    = tid >> 7;                  // row-group: 0 or 1
    const int b     = blockIdx.x >> 1;
    const int chunk = blockIdx.x & 1;
    const int c0    = chunk * 256 + ulane * 2;   // unit/column base (even)

    // Stage broadcast vectors in LDS
    const float* xg = inputs + (size_t)b * INPUT_DIM;
    const float* hg = h_tm1  + (size_t)b * UNITS;
    for (int i = tid; i < INPUT_DIM; i += 256) x_lds[i] = xg[i];
    for (int i = tid; i < UNITS;     i += 256) h_lds[i] = hg[i];
    __syncthreads();

    const float* P  = params + (size_t)b * PARAM_DIM;
    const float* K  = P;              // [512][1536] row-major
    const float* RK = P + NUM_K;      // [512][1536]

    float az0=0.f,az1=0.f, ar0=0.f,ar1=0.f, ah0=0.f,ah1=0.f;  // kernel matvec
    float bz0=0.f,bz1=0.f, br0=0.f,br1=0.f, bh0=0.f,bh1=0.f;  // recurrent matvec

    const int i0 = rg * 256;
    #pragma unroll 4
    for (int i = 0; i < 256; ++i) {
        const int row = i0 + i;
        const float2* kp = (const float2*)(K  + (size_t)row * 1536 + c0);
        const float2* rp = (const float2*)(RK + (size_t)row * 1536 + c0);
        float2 kz = kp[0];   float2 kr = kp[256]; float2 kh = kp[512];
        float2 rz = rp[0];   float2 rr = rp[256]; float2 rh = rp[512];
        float xv = x_lds[row];
        float hv = h_lds[row];
        az0 += xv * kz.x; az1 += xv * kz.y;
        ar0 += xv * kr.x; ar1 += xv * kr.y;
        ah0 += xv * kh.x; ah1 += xv * kh.y;
        bz0 += hv * rz.x; bz1 += hv * rz.y;
        br0 += hv * rr.x; br1 += hv * rr.y;
        bh0 += hv * rh.x; bh1 += hv * rh.y;
    }

    if (rg == 1) {
        float* r = red[ulane];
        r[0]=az0; r[1]=az1; r[2]=ar0; r[3]=ar1; r[4]=ah0; r[5]=ah1;
        r[6]=bz0; r[7]=bz1; r[8]=br0; r[9]=br1; r[10]=bh0; r[11]=bh1;
    }
    __syncthreads();

    if (rg == 0) {
        const float* r = red[ulane];
        az0+=r[0]; az1+=r[1]; ar0+=r[2]; ar1+=r[3]; ah0+=r[4]; ah1+=r[5];
        bz0+=r[6]; bz1+=r[7]; br0+=r[8]; br1+=r[9]; bh0+=r[10]; bh1+=r[11];

        const float* ib = P + NUM_K + NUM_RK;   // input bias [1536]
        const float* rb = ib + 3 * UNITS;       // recurrent bias [1536]

        #pragma unroll
        for (int j = 0; j < 2; ++j) {
            const int c = c0 + j;               // unit index in [0,512)
            const float xz = (j ? az1 : az0) + ib[c];
            const float xr = (j ? ar1 : ar0) + ib[c + 512];
            const float xh = (j ? ah1 : ah0) + ib[c + 1024];
            const float rz = (j ? bz1 : bz0) + rb[c];
            const float rr = (j ? br1 : br0) + rb[c + 512];
            const float rh = (j ? bh1 : bh0) + rb[c + 1024];

            float z = fminf(fmaxf(0.2f * (xz + rz) + 0.5f, 0.0f), 1.0f);
            float rgate = fminf(fmaxf(0.2f * (xr + rr) + 0.5f, 0.0f), 1.0f);
            float hh = tanhf(xh + rgate * rh);
            float hprev = h_lds[c];
            out[(size_t)b * UNITS + c] = z * hprev + (1.0f - z) * hh;
        }
    }
}

extern "C" void kernel_launch(void* const* d_in, const int* in_sizes, int n_in,
                              void* d_out, int out_size, void* d_ws, size_t ws_size,
                              hipStream_t stream) {
    const float* inputs = (const float*)d_in[0];
    const float* params = (const float*)d_in[1];
    const float* h_tm1  = (const float*)d_in[2];
    float* out = (float*)d_out;

    gru_fused<<<dim3(BATCH * 2), dim3(256), 0, stream>>>(inputs, params, h_tm1, out);
}

// Round 4
// 242.184 us; speedup vs baseline: 1.1176x; 1.1176x over previous
//
#include <hip/hip_runtime.h>
#include <math.h>

#define UNITS 512
#define INPUT_DIM 512
#define BATCH 256
#define NUM_K (INPUT_DIM * 3 * UNITS)            // 786432
#define NUM_RK (UNITS * 3 * UNITS)               // 786432
#define NUM_B (2 * 3 * UNITS)                    // 3072
#define PARAM_DIM (NUM_K + NUM_RK + NUM_B)       // 1575936

typedef float v4f __attribute__((ext_vector_type(4)));

// Block: 256 threads = 4 row-groups x 64 unit-lanes; each lane owns 4 units
// (v4f = 16B/lane loads, ideal coalescing). Each block: one (batch,
// 256-unit chunk). Grid = BATCH*2 = 512 blocks -> 2 blocks/CU, 8 waves/CU.
__global__ __launch_bounds__(256) void gru_fused(
    const float* __restrict__ inputs,
    const float* __restrict__ params,
    const float* __restrict__ h_tm1,
    float* __restrict__ out)
{
    __shared__ float x_lds[INPUT_DIM];
    __shared__ float h_lds[UNITS];
    __shared__ float red[3][64][25];   // 24 partials + pad (odd stride: conflict-free)

    const int tid   = threadIdx.x;
    const int ulane = tid & 63;
    const int rg    = tid >> 6;                  // row-group: 0..3
    const int b     = blockIdx.x >> 1;
    const int chunk = blockIdx.x & 1;
    const int c0    = chunk * 256 + ulane * 4;   // unit/column base (mult of 4)

    // Stage broadcast vectors in LDS
    const float* xg = inputs + (size_t)b * INPUT_DIM;
    const float* hg = h_tm1  + (size_t)b * UNITS;
    for (int i = tid; i < INPUT_DIM; i += 256) x_lds[i] = xg[i];
    for (int i = tid; i < UNITS;     i += 256) h_lds[i] = hg[i];
    __syncthreads();

    const float* P  = params + (size_t)b * PARAM_DIM;
    const float* K  = P;              // [512][1536] row-major
    const float* RK = P + NUM_K;      // [512][1536]

    v4f az = {0,0,0,0}, ar = {0,0,0,0}, ah = {0,0,0,0};  // kernel matvec
    v4f bz = {0,0,0,0}, br = {0,0,0,0}, bh = {0,0,0,0};  // recurrent matvec

    const int i0 = rg * 128;
    #pragma unroll 2
    for (int i = 0; i < 128; ++i) {
        const int row = i0 + i;
        const v4f* kp = (const v4f*)(K  + (size_t)row * 1536 + c0);
        const v4f* rp = (const v4f*)(RK + (size_t)row * 1536 + c0);
        v4f kz = __builtin_nontemporal_load(kp);
        v4f kr = __builtin_nontemporal_load(kp + 128);   // +512 floats (gate r)
        v4f kh = __builtin_nontemporal_load(kp + 256);   // +1024 floats (gate h)
        v4f rz = __builtin_nontemporal_load(rp);
        v4f rr = __builtin_nontemporal_load(rp + 128);
        v4f rh = __builtin_nontemporal_load(rp + 256);
        const float xv = x_lds[row];
        const float hv = h_lds[row];
        az += xv * kz;
        ar += xv * kr;
        ah += xv * kh;
        bz += hv * rz;
        br += hv * rr;
        bh += hv * rh;
    }

    if (rg > 0) {
        float* r = &red[rg - 1][ulane][0];
        r[0]=az.x; r[1]=az.y; r[2]=az.z; r[3]=az.w;
        r[4]=ar.x; r[5]=ar.y; r[6]=ar.z; r[7]=ar.w;
        r[8]=ah.x; r[9]=ah.y; r[10]=ah.z; r[11]=ah.w;
        r[12]=bz.x; r[13]=bz.y; r[14]=bz.z; r[15]=bz.w;
        r[16]=br.x; r[17]=br.y; r[18]=br.z; r[19]=br.w;
        r[20]=bh.x; r[21]=bh.y; r[22]=bh.z; r[23]=bh.w;
    }
    __syncthreads();

    if (rg == 0) {
        #pragma unroll
        for (int g = 0; g < 3; ++g) {
            const float* r = &red[g][ulane][0];
            az.x+=r[0]; az.y+=r[1]; az.z+=r[2]; az.w+=r[3];
            ar.x+=r[4]; ar.y+=r[5]; ar.z+=r[6]; ar.w+=r[7];
            ah.x+=r[8]; ah.y+=r[9]; ah.z+=r[10]; ah.w+=r[11];
            bz.x+=r[12]; bz.y+=r[13]; bz.z+=r[14]; bz.w+=r[15];
            br.x+=r[16]; br.y+=r[17]; br.z+=r[18]; br.w+=r[19];
            bh.x+=r[20]; bh.y+=r[21]; bh.z+=r[22]; bh.w+=r[23];
        }

        const float* ib = P + NUM_K + NUM_RK;   // input bias [1536]
        const float* rb = ib + 3 * UNITS;       // recurrent bias [1536]
        const v4f ibz = *(const v4f*)(ib + c0);
        const v4f ibr = *(const v4f*)(ib + c0 + 512);
        const v4f ibh = *(const v4f*)(ib + c0 + 1024);
        const v4f rbz = *(const v4f*)(rb + c0);
        const v4f rbr = *(const v4f*)(rb + c0 + 512);
        const v4f rbh = *(const v4f*)(rb + c0 + 1024);

        const v4f xz = az + ibz;
        const v4f xr = ar + ibr;
        const v4f xh = ah + ibh;
        const v4f rz = bz + rbz;
        const v4f rr = br + rbr;
        const v4f rh = bh + rbh;

        float hout[4];
        #pragma unroll
        for (int j = 0; j < 4; ++j) {
            const float z   = fminf(fmaxf(0.2f * (xz[j] + rz[j]) + 0.5f, 0.0f), 1.0f);
            const float rg_ = fminf(fmaxf(0.2f * (xr[j] + rr[j]) + 0.5f, 0.0f), 1.0f);
            const float hh  = tanhf(xh[j] + rg_ * rh[j]);
            const float hprev = h_lds[c0 + j];
            hout[j] = z * hprev + (1.0f - z) * hh;
        }
        v4f ho = {hout[0], hout[1], hout[2], hout[3]};
        *(v4f*)(out + (size_t)b * UNITS + c0) = ho;
    }
}

extern "C" void kernel_launch(void* const* d_in, const int* in_sizes, int n_in,
                              void* d_out, int out_size, void* d_ws, size_t ws_size,
                              hipStream_t stream) {
    const float* inputs = (const float*)d_in[0];
    const float* params = (const float*)d_in[1];
    const float* h_tm1  = (const float*)d_in[2];
    float* out = (float*)d_out;

    gru_fused<<<dim3(BATCH * 2), dim3(256), 0, stream>>>(inputs, params, h_tm1, out);
}